// Round 1
// baseline (917.193 us; speedup 1.0000x reference)
//
#include <hip/hip_runtime.h>
#include <math.h>

#define Bn 4
#define Sn 2048
#define Dn 1024
#define En 8
#define HDn 128
#define NG (Bn * En)

// ---------------- K1: RoPE + gating (softmax/argmax) ----------------
__global__ __launch_bounds__(256) void k_rope_gate(
    const float* __restrict__ x, const float* __restrict__ Wg,
    const float* __restrict__ cosT, const float* __restrict__ sinT,
    float* __restrict__ xh, int* __restrict__ expertArr, float* __restrict__ gateArr)
{
  int bs = blockIdx.x;              // b*Sn + s
  int s  = bs & (Sn - 1);
  const float* xrow = x + (size_t)bs * Dn;
  float*      xhrow = xh + (size_t)bs * Dn;
  int t = threadIdx.x;
  int j = t << 2;                   // 4 elements per thread
  int hbase = j & ~127;             // head base (h*128)
  int jj = j & 127;
  float v0, v1, v2, v3;
  if (jj < 64) {
    // rotated part comes from x[..., 64:128]
    const float* pe = xrow + hbase + 64 + jj;
    float a0 = pe[0], a1 = pe[1], a2 = pe[2], a3 = pe[3];
    int p0 = jj >> 1;
    float c0 = cosT[s * 32 + p0],     s0 = sinT[s * 32 + p0];
    float c1 = cosT[s * 32 + p0 + 1], s1 = sinT[s * 32 + p0 + 1];
    v0 = a0 * c0 - a1 * s0;
    v1 = a0 * s0 + a1 * c0;
    v2 = a2 * c1 - a3 * s1;
    v3 = a2 * s1 + a3 * c1;
  } else {
    // nope part = x[..., 0:64]
    const float* np = xrow + hbase + (jj - 64);
    v0 = np[0]; v1 = np[1]; v2 = np[2]; v3 = np[3];
  }
  *(float4*)(xhrow + j) = make_float4(v0, v1, v2, v3);

  // gating partial dot products: logits[e] = xh_row . Wg[:,e]
  float pl[En];
  const float* wr = Wg + (size_t)j * En;
#pragma unroll
  for (int e = 0; e < En; ++e)
    pl[e] = v0 * wr[e] + v1 * wr[En + e] + v2 * wr[2 * En + e] + v3 * wr[3 * En + e];
#pragma unroll
  for (int off = 1; off < 64; off <<= 1) {
#pragma unroll
    for (int e = 0; e < En; ++e) pl[e] += __shfl_xor(pl[e], off, 64);
  }
  __shared__ float red[4][En];
  int wv = t >> 6, ln = t & 63;
  if (ln == 0) {
#pragma unroll
    for (int e = 0; e < En; ++e) red[wv][e] = pl[e];
  }
  __syncthreads();
  if (t == 0) {
    float l[En];
    for (int e = 0; e < En; ++e) l[e] = red[0][e] + red[1][e] + red[2][e] + red[3][e];
    float m = l[0]; int be = 0;
    for (int e = 1; e < En; ++e) if (l[e] > m) { m = l[e]; be = e; }  // first max wins
    float ss = 0.f;
    for (int e = 0; e < En; ++e) ss += expf(l[e] - m);
    expertArr[bs] = be;
    gateArr[bs] = 1.0f / ss;       // max prob = exp(0)/sum
  }
}

// ---------------- K2: stable per-(b,e) token lists ----------------
__global__ __launch_bounds__(256) void k_route(
    const int* __restrict__ expertArr, int* __restrict__ idx, int* __restrict__ cnt)
{
  int g = blockIdx.x;               // b*En + e
  int b = g >> 3, e = g & 7;
  int t = threadIdx.x;
  __shared__ int wtot[4];
  __shared__ int base;
  if (t == 0) base = 0;
  __syncthreads();
  for (int c = 0; c < Sn; c += 256) {
    int s = c + t;
    int pred = (expertArr[b * Sn + s] == e) ? 1 : 0;
    unsigned long long mask = __ballot(pred);
    int ln = t & 63, wv = t >> 6;
    int wpre = __popcll(mask & ((1ull << ln) - 1ull));
    if (ln == 63) wtot[wv] = wpre + pred;
    __syncthreads();                // wtot + previous base visible
    int woff = 0;
    for (int w = 0; w < wv; ++w) woff += wtot[w];
    int tot = wtot[0] + wtot[1] + wtot[2] + wtot[3];
    if (pred) idx[(g << 11) + base + woff + wpre] = s;
    __syncthreads();                // all reads of base done
    if (t == 0) base += tot;
    __syncthreads();
  }
  if (t == 0) cnt[g] = base;
}

// ---------------- K3: grouped QKV GEMM (64x64 tile, K=1024, BK=16) ----------------
__global__ __launch_bounds__(256) void k_qkv(
    const float* __restrict__ xh, const float* __restrict__ Wqkv,
    const int* __restrict__ idx, const int* __restrict__ cnt,
    float* __restrict__ qkv)
{
  int g = blockIdx.y;
  int n = cnt[g];
  int m0 = blockIdx.x << 6;
  if (m0 >= n) return;
  int b = g >> 3, e = g & 7;
  int n0 = blockIdx.z << 6;         // 6 tiles cover 384 cols
  __shared__ float As[64][17];      // [m][k], pad 17 -> conflict-free
  __shared__ float Bs[16][64];      // [k][c]
  int t = threadIdx.x;
  int tx = t & 15, ty = t >> 4;
  float acc[4][4];
#pragma unroll
  for (int i = 0; i < 4; ++i)
#pragma unroll
    for (int q = 0; q < 4; ++q) acc[i][q] = 0.f;

  int mload = t >> 2, kq = (t & 3) << 2;
  int rowg = m0 + mload;
  bool avalid = (rowg < n);
  const float* arow = avalid ? (xh + ((size_t)(b * Sn + idx[(g << 11) + rowg]) << 10)) : xh;
  int kb = t >> 4, cb = tx << 2;
  const float* bbase = Wqkv + (((size_t)e << 10) + kb) * 384 + n0 + cb;

  for (int k0 = 0; k0 < Dn; k0 += 16) {
    float4 av = make_float4(0.f, 0.f, 0.f, 0.f);
    if (avalid) av = *(const float4*)(arow + k0 + kq);
    As[mload][kq + 0] = av.x; As[mload][kq + 1] = av.y;
    As[mload][kq + 2] = av.z; As[mload][kq + 3] = av.w;
    *(float4*)(&Bs[kb][cb]) = *(const float4*)(bbase + (size_t)k0 * 384);
    __syncthreads();
#pragma unroll
    for (int k = 0; k < 16; ++k) {
      float a0 = As[ty * 4 + 0][k], a1 = As[ty * 4 + 1][k];
      float a2 = As[ty * 4 + 2][k], a3 = As[ty * 4 + 3][k];
      float4 b4 = *(const float4*)(&Bs[k][tx << 2]);
      acc[0][0] += a0 * b4.x; acc[0][1] += a0 * b4.y; acc[0][2] += a0 * b4.z; acc[0][3] += a0 * b4.w;
      acc[1][0] += a1 * b4.x; acc[1][1] += a1 * b4.y; acc[1][2] += a1 * b4.z; acc[1][3] += a1 * b4.w;
      acc[2][0] += a2 * b4.x; acc[2][1] += a2 * b4.y; acc[2][2] += a2 * b4.z; acc[2][3] += a2 * b4.w;
      acc[3][0] += a3 * b4.x; acc[3][1] += a3 * b4.y; acc[3][2] += a3 * b4.z; acc[3][3] += a3 * b4.w;
    }
    __syncthreads();
  }
#pragma unroll
  for (int i = 0; i < 4; ++i) {
    int rg = m0 + ty * 4 + i;
    if (rg < n) {
      int tok = idx[(g << 11) + rg];
      float* orow = qkv + (size_t)(b * Sn + tok) * 384 + n0 + (tx << 2);
      *(float4*)orow = make_float4(acc[i][0], acc[i][1], acc[i][2], acc[i][3]);
    }
  }
}

// ---------------- K4: grouped flash attention (32 q x 32 k tiles) ----------------
__global__ __launch_bounds__(256) void k_attn(
    const float* __restrict__ qkv, const int* __restrict__ idx,
    const int* __restrict__ cnt, float* __restrict__ ctx)
{
  int g = blockIdx.y;
  int n = cnt[g];
  int m0 = blockIdx.x << 5;
  if (m0 >= n) return;
  int b = g >> 3;
  __shared__ float Qs[32][132];
  __shared__ float Ks[32][132];     // XOR-swizzled 16B blocks
  __shared__ float Vs[32][132];
  __shared__ float Ps[32][36];
  int t = threadIdx.x;
  {
    int q = t >> 3, c0 = (t & 7) << 2;
    int rg = m0 + q;
    bool v = (rg < n);
    const float* qrow = v ? (qkv + (size_t)(b * Sn + idx[(g << 11) + rg]) * 384) : qkv;
#pragma unroll
    for (int jt = 0; jt < 4; ++jt) {
      int c = c0 + (jt << 5);
      float4 vq = v ? *(const float4*)(qrow + c) : make_float4(0.f, 0.f, 0.f, 0.f);
      *(float4*)(&Qs[q][c]) = vq;
    }
  }
  int q = t >> 3, kk = t & 7;
  float m_r = -1e30f, l_r = 0.f;
  float acc[16];
#pragma unroll
  for (int i = 0; i < 16; ++i) acc[i] = 0.f;
  const float scale = 0.08838834764831845f;   // 1/sqrt(128)

  for (int kc = 0; kc < n; kc += 32) {
    {
      int kr = t >> 3, c0 = (t & 7) << 2;
      int kg = kc + kr;
      bool v = (kg < n);
      const float* krow = v ? (qkv + (size_t)(b * Sn + idx[(g << 11) + kg]) * 384 + 128) : qkv;
      int sw = (kr >> 2) & 7;
#pragma unroll
      for (int jt = 0; jt < 4; ++jt) {
        int c = c0 + (jt << 5);
        float4 kv = v ? *(const float4*)(krow + c) : make_float4(0.f, 0.f, 0.f, 0.f);
        int cb = c >> 2;
        *(float4*)(&Ks[kr][(cb ^ sw) << 2]) = kv;      // swizzled store
        float4 vv = v ? *(const float4*)(krow + 128 + c) : make_float4(0.f, 0.f, 0.f, 0.f);
        *(float4*)(&Vs[kr][c]) = vv;
      }
    }
    __syncthreads();
    float sv[4] = {0.f, 0.f, 0.f, 0.f};
#pragma unroll
    for (int d4 = 0; d4 < 128; d4 += 4) {
      float4 qv = *(const float4*)(&Qs[q][d4]);
      int cbs = ((d4 >> 2) ^ kk) << 2;                 // swizzled read col for rows kk*4..+3
#pragma unroll
      for (int jj = 0; jj < 4; ++jj) {
        float4 kv = *(const float4*)(&Ks[kk * 4 + jj][cbs]);
        sv[jj] += qv.x * kv.x + qv.y * kv.y + qv.z * kv.z + qv.w * kv.w;
      }
    }
    float mloc = -1e30f;
#pragma unroll
    for (int jj = 0; jj < 4; ++jj) {
      int kg = kc + kk * 4 + jj;
      sv[jj] = (kg < n) ? sv[jj] * scale : -1e30f;
      mloc = fmaxf(mloc, sv[jj]);
    }
    mloc = fmaxf(mloc, __shfl_xor(mloc, 1, 64));
    mloc = fmaxf(mloc, __shfl_xor(mloc, 2, 64));
    mloc = fmaxf(mloc, __shfl_xor(mloc, 4, 64));
    float m_new = fmaxf(m_r, mloc);
    float corr = expf(m_r - m_new);
    float rs = 0.f;
#pragma unroll
    for (int jj = 0; jj < 4; ++jj) {
      float p = expf(sv[jj] - m_new);
      Ps[q][kk * 4 + jj] = p;
      rs += p;
    }
    rs += __shfl_xor(rs, 1, 64);
    rs += __shfl_xor(rs, 2, 64);
    rs += __shfl_xor(rs, 4, 64);
    l_r = l_r * corr + rs;
    m_r = m_new;
#pragma unroll
    for (int i = 0; i < 16; ++i) acc[i] *= corr;
    __syncthreads();                 // Ps visible
#pragma unroll
    for (int key = 0; key < 32; ++key) {
      float pv = Ps[q][key];
      const float* vr = &Vs[key][kk << 4];
#pragma unroll
      for (int i4 = 0; i4 < 4; ++i4) {
        float4 vv = *(const float4*)(vr + (i4 << 2));
        acc[i4 * 4 + 0] += pv * vv.x;
        acc[i4 * 4 + 1] += pv * vv.y;
        acc[i4 * 4 + 2] += pv * vv.z;
        acc[i4 * 4 + 3] += pv * vv.w;
      }
    }
    __syncthreads();                 // protect Ks/Vs/Ps before next chunk
  }
  int rg = m0 + q;
  if (rg < n) {
    int tok = idx[(g << 11) + rg];
    float inv = 1.0f / l_r;
    float* orow = ctx + ((size_t)(b * Sn + tok) << 7) + (kk << 4);
#pragma unroll
    for (int i4 = 0; i4 < 4; ++i4) {
      *(float4*)(orow + (i4 << 2)) = make_float4(acc[i4 * 4 + 0] * inv, acc[i4 * 4 + 1] * inv,
                                                 acc[i4 * 4 + 2] * inv, acc[i4 * 4 + 3] * inv);
    }
  }
}

// ---------------- K5: out projection + gate + scatter ----------------
__global__ __launch_bounds__(256) void k_out(
    const float* __restrict__ ctx, const float* __restrict__ Wff,
    const float* __restrict__ bff, const int* __restrict__ idx,
    const int* __restrict__ cnt, const float* __restrict__ gateArr,
    float* __restrict__ out)
{
  int g = blockIdx.y;
  int n = cnt[g];
  int m0 = blockIdx.x << 5;
  if (m0 >= n) return;
  int b = g >> 3, e = g & 7;
  int n0 = blockIdx.z << 7;          // 8 tiles of 128 cols
  __shared__ float Cs[32][132];
  __shared__ float Ws[32][128];
  int t = threadIdx.x;
  int r0 = (t >> 5) << 2;
  int c0 = (t & 31) << 2;
  float acc[4][4];
#pragma unroll
  for (int i = 0; i < 4; ++i)
#pragma unroll
    for (int q = 0; q < 4; ++q) acc[i][q] = 0.f;
  {
    int r = t >> 3, cq = (t & 7) << 2;
    int rg = m0 + r;
    bool v = (rg < n);
    const float* crow = v ? (ctx + ((size_t)(b * Sn + idx[(g << 11) + rg]) << 7)) : ctx;
#pragma unroll
    for (int jt = 0; jt < 4; ++jt) {
      int c = cq + (jt << 5);
      float4 cv = v ? *(const float4*)(crow + c) : make_float4(0.f, 0.f, 0.f, 0.f);
      *(float4*)(&Cs[r][c]) = cv;
    }
  }
  for (int k0 = 0; k0 < 128; k0 += 32) {
    int kr = t >> 3, cq = (t & 7) << 2;
    const float* wrow = Wff + ((size_t)e * 128 + k0 + kr) * 1024 + n0;
#pragma unroll
    for (int jt = 0; jt < 4; ++jt) {
      int c = cq + (jt << 5);
      *(float4*)(&Ws[kr][c]) = *(const float4*)(wrow + c);
    }
    __syncthreads();
#pragma unroll
    for (int k = 0; k < 32; ++k) {
      float4 b4 = *(const float4*)(&Ws[k][c0]);
      float a0 = Cs[r0 + 0][k0 + k], a1 = Cs[r0 + 1][k0 + k];
      float a2 = Cs[r0 + 2][k0 + k], a3 = Cs[r0 + 3][k0 + k];
      acc[0][0] += a0 * b4.x; acc[0][1] += a0 * b4.y; acc[0][2] += a0 * b4.z; acc[0][3] += a0 * b4.w;
      acc[1][0] += a1 * b4.x; acc[1][1] += a1 * b4.y; acc[1][2] += a1 * b4.z; acc[1][3] += a1 * b4.w;
      acc[2][0] += a2 * b4.x; acc[2][1] += a2 * b4.y; acc[2][2] += a2 * b4.z; acc[2][3] += a2 * b4.w;
      acc[3][0] += a3 * b4.x; acc[3][1] += a3 * b4.y; acc[3][2] += a3 * b4.z; acc[3][3] += a3 * b4.w;
    }
    __syncthreads();
  }
  float4 bv = *(const float4*)(bff + n0 + c0);
#pragma unroll
  for (int i = 0; i < 4; ++i) {
    int rg = m0 + r0 + i;
    if (rg < n) {
      int tok = idx[(g << 11) + rg];
      float gt = gateArr[b * Sn + tok];
      float* orow = out + ((size_t)(b * Sn + tok) << 10) + n0 + c0;
      *(float4*)orow = make_float4((acc[i][0] + bv.x) * gt, (acc[i][1] + bv.y) * gt,
                                   (acc[i][2] + bv.z) * gt, (acc[i][3] + bv.w) * gt);
    }
  }
}

extern "C" void kernel_launch(void* const* d_in, const int* in_sizes, int n_in,
                              void* d_out, int out_size, void* d_ws, size_t ws_size,
                              hipStream_t stream) {
  const float* x    = (const float*)d_in[0];
  const float* Wg   = (const float*)d_in[1];
  const float* Wqkv = (const float*)d_in[2];
  const float* Wff  = (const float*)d_in[3];
  const float* bff  = (const float*)d_in[4];
  const float* cosT = (const float*)d_in[5];
  const float* sinT = (const float*)d_in[6];
  float* out = (float*)d_out;

  size_t off = 0;
  auto carve = [&](size_t bytes) -> void* {
    void* p = (char*)d_ws + off;
    off += (bytes + 255) & ~(size_t)255;
    return p;
  };
  float* xh      = (float*)carve((size_t)Bn * Sn * Dn * sizeof(float));
  float* qkv     = (float*)carve((size_t)Bn * Sn * 384 * sizeof(float));
  float* ctx     = (float*)carve((size_t)Bn * Sn * HDn * sizeof(float));
  float* gateArr = (float*)carve((size_t)Bn * Sn * sizeof(float));
  int*   expertA = (int*)carve((size_t)Bn * Sn * sizeof(int));
  int*   idx     = (int*)carve((size_t)NG * Sn * sizeof(int));
  int*   cnt     = (int*)carve((size_t)NG * sizeof(int));
  (void)ws_size; (void)in_sizes; (void)n_in; (void)out_size;

  k_rope_gate<<<dim3(Bn * Sn), dim3(256), 0, stream>>>(x, Wg, cosT, sinT, xh, expertA, gateArr);
  k_route<<<dim3(NG), dim3(256), 0, stream>>>(expertA, idx, cnt);
  k_qkv<<<dim3(Sn / 64, NG, 6), dim3(256), 0, stream>>>(xh, Wqkv, idx, cnt, qkv);
  k_attn<<<dim3(Sn / 32, NG), dim3(256), 0, stream>>>(qkv, idx, cnt, ctx);
  k_out<<<dim3(Sn / 32, NG, 8), dim3(256), 0, stream>>>(ctx, Wff, bff, idx, cnt, gateArr, out);
}

// Round 2
// 742.255 us; speedup vs baseline: 1.2357x; 1.2357x over previous
//
#include <hip/hip_runtime.h>
#include <math.h>

#define Bn 4
#define Sn 2048
#define Dn 1024
#define En 8
#define HDn 128
#define NG (Bn * En)

typedef __attribute__((ext_vector_type(8))) short bf16x8;
typedef __attribute__((ext_vector_type(4))) float f32x4;

__device__ __forceinline__ unsigned bf16_rn(float x) {
  unsigned u = __float_as_uint(x);
  return (u + 0x7fffu + ((u >> 16) & 1u)) >> 16;
}
__device__ __forceinline__ void bsplit(float x, unsigned& hi, unsigned& lo) {
  hi = bf16_rn(x);
  float hf = __uint_as_float(hi << 16);
  lo = bf16_rn(x - hf);
}

// ---------------- K1: RoPE + gating; emits xh as bf16 hi/lo ----------------
__global__ __launch_bounds__(256) void k_rope_gate(
    const float* __restrict__ x, const float* __restrict__ Wg,
    const float* __restrict__ cosT, const float* __restrict__ sinT,
    unsigned short* __restrict__ xh_hi, unsigned short* __restrict__ xh_lo,
    int* __restrict__ expertArr, float* __restrict__ gateArr)
{
  int bs = blockIdx.x;              // b*Sn + s
  int s  = bs & (Sn - 1);
  const float* xrow = x + (size_t)bs * Dn;
  int t = threadIdx.x;
  int j = t << 2;                   // 4 elements per thread
  int hbase = j & ~127;             // head base (h*128)
  int jj = j & 127;
  float v0, v1, v2, v3;
  if (jj < 64) {
    const float* pe = xrow + hbase + 64 + jj;
    float a0 = pe[0], a1 = pe[1], a2 = pe[2], a3 = pe[3];
    int p0 = jj >> 1;
    float c0 = cosT[s * 32 + p0],     s0 = sinT[s * 32 + p0];
    float c1 = cosT[s * 32 + p0 + 1], s1 = sinT[s * 32 + p0 + 1];
    v0 = a0 * c0 - a1 * s0;
    v1 = a0 * s0 + a1 * c0;
    v2 = a2 * c1 - a3 * s1;
    v3 = a2 * s1 + a3 * c1;
  } else {
    const float* np = xrow + hbase + (jj - 64);
    v0 = np[0]; v1 = np[1]; v2 = np[2]; v3 = np[3];
  }
  unsigned h0,l0,h1,l1,h2,l2,h3,l3;
  bsplit(v0,h0,l0); bsplit(v1,h1,l1); bsplit(v2,h2,l2); bsplit(v3,h3,l3);
  ushort4 H = make_ushort4((unsigned short)h0,(unsigned short)h1,(unsigned short)h2,(unsigned short)h3);
  ushort4 L = make_ushort4((unsigned short)l0,(unsigned short)l1,(unsigned short)l2,(unsigned short)l3);
  *(ushort4*)(xh_hi + (size_t)bs * Dn + j) = H;
  *(ushort4*)(xh_lo + (size_t)bs * Dn + j) = L;

  // gating partial dot products (fp32): logits[e] = xh_row . Wg[:,e]
  float pl[En];
  const float* wr = Wg + (size_t)j * En;
#pragma unroll
  for (int e = 0; e < En; ++e)
    pl[e] = v0 * wr[e] + v1 * wr[En + e] + v2 * wr[2 * En + e] + v3 * wr[3 * En + e];
#pragma unroll
  for (int off = 1; off < 64; off <<= 1) {
#pragma unroll
    for (int e = 0; e < En; ++e) pl[e] += __shfl_xor(pl[e], off, 64);
  }
  __shared__ float red[4][En];
  int wv = t >> 6, ln = t & 63;
  if (ln == 0) {
#pragma unroll
    for (int e = 0; e < En; ++e) red[wv][e] = pl[e];
  }
  __syncthreads();
  if (t == 0) {
    float l[En];
    for (int e = 0; e < En; ++e) l[e] = red[0][e] + red[1][e] + red[2][e] + red[3][e];
    float m = l[0]; int be = 0;
    for (int e = 1; e < En; ++e) if (l[e] > m) { m = l[e]; be = e; }  // first max wins
    float ss = 0.f;
    for (int e = 0; e < En; ++e) ss += expf(l[e] - m);
    expertArr[bs] = be;
    gateArr[bs] = 1.0f / ss;
  }
}

// ---------------- K1b: transpose+split Wqkv -> [e][col=384][k=1024] bf16 hi/lo ----------------
__global__ __launch_bounds__(256) void k_prep_w(
    const float* __restrict__ W, unsigned short* __restrict__ hiT, unsigned short* __restrict__ loT)
{
  int e = blockIdx.z, k0 = blockIdx.x << 6, c0 = blockIdx.y << 6;
  __shared__ float tile[64][65];
  int t = threadIdx.x;
  int r = t >> 4, cc = (t & 15) << 2;
  const float* src = W + ((size_t)e * Dn + k0) * 384 + c0;
#pragma unroll
  for (int i = 0; i < 4; ++i) {
    float4 v = *(const float4*)(src + (size_t)(r + i * 16) * 384 + cc);
    tile[r + i * 16][cc + 0] = v.x; tile[r + i * 16][cc + 1] = v.y;
    tile[r + i * 16][cc + 2] = v.z; tile[r + i * 16][cc + 3] = v.w;
  }
  __syncthreads();
#pragma unroll
  for (int i = 0; i < 4; ++i) {
    int oc = (t >> 4) + i * 16;     // col within tile
    int ok = (t & 15) << 2;         // k within tile
    float v0 = tile[ok + 0][oc], v1 = tile[ok + 1][oc];
    float v2 = tile[ok + 2][oc], v3 = tile[ok + 3][oc];
    unsigned h0,l0,h1,l1,h2,l2,h3,l3;
    bsplit(v0,h0,l0); bsplit(v1,h1,l1); bsplit(v2,h2,l2); bsplit(v3,h3,l3);
    size_t o = ((size_t)e * 384 + c0 + oc) * Dn + k0 + ok;
    *(ushort4*)(hiT + o) = make_ushort4((unsigned short)h0,(unsigned short)h1,(unsigned short)h2,(unsigned short)h3);
    *(ushort4*)(loT + o) = make_ushort4((unsigned short)l0,(unsigned short)l1,(unsigned short)l2,(unsigned short)l3);
  }
}

// ---------------- K2: stable per-(b,e) token lists ----------------
__global__ __launch_bounds__(256) void k_route(
    const int* __restrict__ expertArr, int* __restrict__ idx, int* __restrict__ cnt)
{
  int g = blockIdx.x;               // b*En + e
  int b = g >> 3, e = g & 7;
  int t = threadIdx.x;
  __shared__ int wtot[4];
  __shared__ int base;
  if (t == 0) base = 0;
  __syncthreads();
  for (int c = 0; c < Sn; c += 256) {
    int s = c + t;
    int pred = (expertArr[b * Sn + s] == e) ? 1 : 0;
    unsigned long long mask = __ballot(pred);
    int ln = t & 63, wv = t >> 6;
    int wpre = __popcll(mask & ((1ull << ln) - 1ull));
    if (ln == 63) wtot[wv] = wpre + pred;
    __syncthreads();
    int woff = 0;
    for (int w = 0; w < wv; ++w) woff += wtot[w];
    int tot = wtot[0] + wtot[1] + wtot[2] + wtot[3];
    if (pred) idx[(g << 11) + base + woff + wpre] = s;
    __syncthreads();
    if (t == 0) base += tot;
    __syncthreads();
  }
  if (t == 0) cnt[g] = base;
}

// ---------------- K3: grouped QKV GEMM via MFMA bf16x3 split ----------------
// Block tile 64 rows x 384 cols, 4 waves each 64x96. A,B loaded directly from
// global (A: gathered rows, 16B/lane; B: pre-transposed weights, L2-resident).
__global__ __launch_bounds__(256) void k_qkv(
    const unsigned short* __restrict__ xh_hi, const unsigned short* __restrict__ xh_lo,
    const unsigned short* __restrict__ WqT_hi, const unsigned short* __restrict__ WqT_lo,
    const int* __restrict__ idx, const int* __restrict__ cnt,
    float* __restrict__ qkv)
{
  int g = blockIdx.y;
  int n = cnt[g];
  int m0 = blockIdx.x << 6;
  if (m0 >= n) return;
  int b = g >> 3, e = g & 7;
  const int* idxg = idx + (g << 11);
  int t = threadIdx.x;
  int wid = t >> 6, lane = t & 63;
  int laneq = lane >> 4, lanec = lane & 15;

  f32x4 acc[4][6];
#pragma unroll
  for (int fi = 0; fi < 4; ++fi)
#pragma unroll
    for (int fj = 0; fj < 6; ++fj) acc[fi][fj] = (f32x4){0.f, 0.f, 0.f, 0.f};

  // A fragment row offsets (elements): row = b*Sn + tok, plus laneq*8 within k
  size_t aoff[4];
#pragma unroll
  for (int fi = 0; fi < 4; ++fi) {
    int rg = m0 + fi * 16 + lanec;
    rg = (rg < n) ? rg : (n - 1);
    int tok = idxg[rg];
    aoff[fi] = ((size_t)(b * Sn + tok)) * Dn + laneq * 8;
  }
  // B offset (elements): col = wid*96 + fj*16 + lanec; addr = (e*384+col)*1024 + laneq*8 + k0
  size_t boff = ((size_t)e * 384 + wid * 96 + lanec) * Dn + laneq * 8;

#pragma unroll
  for (int pass = 0; pass < 3; ++pass) {
    const unsigned short* A = (pass == 1) ? xh_lo : xh_hi;
    const unsigned short* Bp = ((pass == 2) ? WqT_lo : WqT_hi) + boff;
    for (int k0 = 0; k0 < Dn; k0 += 32) {
      bf16x8 a[4];
#pragma unroll
      for (int fi = 0; fi < 4; ++fi)
        a[fi] = *(const bf16x8*)(A + aoff[fi] + k0);
#pragma unroll
      for (int fj = 0; fj < 6; ++fj) {
        bf16x8 bv = *(const bf16x8*)(Bp + fj * 16 * Dn + k0);
#pragma unroll
        for (int fi = 0; fi < 4; ++fi)
          acc[fi][fj] = __builtin_amdgcn_mfma_f32_16x16x32_bf16(a[fi], bv, acc[fi][fj], 0, 0, 0);
      }
    }
  }

  // store: C row within frag = laneq*4 + r, col = lanec
#pragma unroll
  for (int fi = 0; fi < 4; ++fi) {
#pragma unroll
    for (int r = 0; r < 4; ++r) {
      int rg = m0 + fi * 16 + laneq * 4 + r;
      if (rg < n) {
        int tok = idxg[rg];
        float* orow = qkv + (size_t)(b * Sn + tok) * 384 + wid * 96 + lanec;
#pragma unroll
        for (int fj = 0; fj < 6; ++fj) orow[fj * 16] = acc[fi][fj][r];
      }
    }
  }
}

// ---------------- K4: grouped flash attention (32 q x 32 k tiles) ----------------
__global__ __launch_bounds__(256) void k_attn(
    const float* __restrict__ qkv, const int* __restrict__ idx,
    const int* __restrict__ cnt, float* __restrict__ ctx)
{
  int g = blockIdx.y;
  int n = cnt[g];
  int m0 = blockIdx.x << 5;
  if (m0 >= n) return;
  int b = g >> 3;
  __shared__ float Qs[32][132];
  __shared__ float Ks[32][132];     // XOR-swizzled 16B blocks
  __shared__ float Vs[32][132];
  __shared__ float Ps[32][36];
  int t = threadIdx.x;
  {
    int q = t >> 3, c0 = (t & 7) << 2;
    int rg = m0 + q;
    bool v = (rg < n);
    const float* qrow = v ? (qkv + (size_t)(b * Sn + idx[(g << 11) + rg]) * 384) : qkv;
#pragma unroll
    for (int jt = 0; jt < 4; ++jt) {
      int c = c0 + (jt << 5);
      float4 vq = v ? *(const float4*)(qrow + c) : make_float4(0.f, 0.f, 0.f, 0.f);
      *(float4*)(&Qs[q][c]) = vq;
    }
  }
  int q = t >> 3, kk = t & 7;
  float m_r = -1e30f, l_r = 0.f;
  float acc[16];
#pragma unroll
  for (int i = 0; i < 16; ++i) acc[i] = 0.f;
  const float scale = 0.08838834764831845f;   // 1/sqrt(128)

  for (int kc = 0; kc < n; kc += 32) {
    {
      int kr = t >> 3, c0 = (t & 7) << 2;
      int kg = kc + kr;
      bool v = (kg < n);
      const float* krow = v ? (qkv + (size_t)(b * Sn + idx[(g << 11) + kg]) * 384 + 128) : qkv;
      int sw = (kr >> 2) & 7;
#pragma unroll
      for (int jt = 0; jt < 4; ++jt) {
        int c = c0 + (jt << 5);
        float4 kv = v ? *(const float4*)(krow + c) : make_float4(0.f, 0.f, 0.f, 0.f);
        int cb = c >> 2;
        *(float4*)(&Ks[kr][(cb ^ sw) << 2]) = kv;      // swizzled store
        float4 vv = v ? *(const float4*)(krow + 128 + c) : make_float4(0.f, 0.f, 0.f, 0.f);
        *(float4*)(&Vs[kr][c]) = vv;
      }
    }
    __syncthreads();
    float sv[4] = {0.f, 0.f, 0.f, 0.f};
#pragma unroll
    for (int d4 = 0; d4 < 128; d4 += 4) {
      float4 qv = *(const float4*)(&Qs[q][d4]);
      int cbs = ((d4 >> 2) ^ kk) << 2;
#pragma unroll
      for (int jj = 0; jj < 4; ++jj) {
        float4 kv = *(const float4*)(&Ks[kk * 4 + jj][cbs]);
        sv[jj] += qv.x * kv.x + qv.y * kv.y + qv.z * kv.z + qv.w * kv.w;
      }
    }
    float mloc = -1e30f;
#pragma unroll
    for (int jj = 0; jj < 4; ++jj) {
      int kg = kc + kk * 4 + jj;
      sv[jj] = (kg < n) ? sv[jj] * scale : -1e30f;
      mloc = fmaxf(mloc, sv[jj]);
    }
    mloc = fmaxf(mloc, __shfl_xor(mloc, 1, 64));
    mloc = fmaxf(mloc, __shfl_xor(mloc, 2, 64));
    mloc = fmaxf(mloc, __shfl_xor(mloc, 4, 64));
    float m_new = fmaxf(m_r, mloc);
    float corr = expf(m_r - m_new);
    float rs = 0.f;
#pragma unroll
    for (int jj = 0; jj < 4; ++jj) {
      float p = expf(sv[jj] - m_new);
      Ps[q][kk * 4 + jj] = p;
      rs += p;
    }
    rs += __shfl_xor(rs, 1, 64);
    rs += __shfl_xor(rs, 2, 64);
    rs += __shfl_xor(rs, 4, 64);
    l_r = l_r * corr + rs;
    m_r = m_new;
#pragma unroll
    for (int i = 0; i < 16; ++i) acc[i] *= corr;
    __syncthreads();
#pragma unroll
    for (int key = 0; key < 32; ++key) {
      float pv = Ps[q][key];
      const float* vr = &Vs[key][kk << 4];
#pragma unroll
      for (int i4 = 0; i4 < 4; ++i4) {
        float4 vv = *(const float4*)(vr + (i4 << 2));
        acc[i4 * 4 + 0] += pv * vv.x;
        acc[i4 * 4 + 1] += pv * vv.y;
        acc[i4 * 4 + 2] += pv * vv.z;
        acc[i4 * 4 + 3] += pv * vv.w;
      }
    }
    __syncthreads();
  }
  int rg = m0 + q;
  if (rg < n) {
    int tok = idx[(g << 11) + rg];
    float inv = 1.0f / l_r;
    float* orow = ctx + ((size_t)(b * Sn + tok) << 7) + (kk << 4);
#pragma unroll
    for (int i4 = 0; i4 < 4; ++i4) {
      *(float4*)(orow + (i4 << 2)) = make_float4(acc[i4 * 4 + 0] * inv, acc[i4 * 4 + 1] * inv,
                                                 acc[i4 * 4 + 2] * inv, acc[i4 * 4 + 3] * inv);
    }
  }
}

// ---------------- K5: out projection + gate + scatter ----------------
__global__ __launch_bounds__(256) void k_out(
    const float* __restrict__ ctx, const float* __restrict__ Wff,
    const float* __restrict__ bff, const int* __restrict__ idx,
    const int* __restrict__ cnt, const float* __restrict__ gateArr,
    float* __restrict__ out)
{
  int g = blockIdx.y;
  int n = cnt[g];
  int m0 = blockIdx.x << 5;
  if (m0 >= n) return;
  int b = g >> 3, e = g & 7;
  int n0 = blockIdx.z << 7;
  __shared__ float Cs[32][132];
  __shared__ float Ws[32][128];
  int t = threadIdx.x;
  int r0 = (t >> 5) << 2;
  int c0 = (t & 31) << 2;
  float acc[4][4];
#pragma unroll
  for (int i = 0; i < 4; ++i)
#pragma unroll
    for (int q = 0; q < 4; ++q) acc[i][q] = 0.f;
  {
    int r = t >> 3, cq = (t & 7) << 2;
    int rg = m0 + r;
    bool v = (rg < n);
    const float* crow = v ? (ctx + ((size_t)(b * Sn + idx[(g << 11) + rg]) << 7)) : ctx;
#pragma unroll
    for (int jt = 0; jt < 4; ++jt) {
      int c = cq + (jt << 5);
      float4 cv = v ? *(const float4*)(crow + c) : make_float4(0.f, 0.f, 0.f, 0.f);
      *(float4*)(&Cs[r][c]) = cv;
    }
  }
  for (int k0 = 0; k0 < 128; k0 += 32) {
    int kr = t >> 3, cq = (t & 7) << 2;
    const float* wrow = Wff + ((size_t)e * 128 + k0 + kr) * 1024 + n0;
#pragma unroll
    for (int jt = 0; jt < 4; ++jt) {
      int c = cq + (jt << 5);
      *(float4*)(&Ws[kr][c]) = *(const float4*)(wrow + c);
    }
    __syncthreads();
#pragma unroll
    for (int k = 0; k < 32; ++k) {
      float4 b4 = *(const float4*)(&Ws[k][c0]);
      float a0 = Cs[r0 + 0][k0 + k], a1 = Cs[r0 + 1][k0 + k];
      float a2 = Cs[r0 + 2][k0 + k], a3 = Cs[r0 + 3][k0 + k];
      acc[0][0] += a0 * b4.x; acc[0][1] += a0 * b4.y; acc[0][2] += a0 * b4.z; acc[0][3] += a0 * b4.w;
      acc[1][0] += a1 * b4.x; acc[1][1] += a1 * b4.y; acc[1][2] += a1 * b4.z; acc[1][3] += a1 * b4.w;
      acc[2][0] += a2 * b4.x; acc[2][1] += a2 * b4.y; acc[2][2] += a2 * b4.z; acc[2][3] += a2 * b4.w;
      acc[3][0] += a3 * b4.x; acc[3][1] += a3 * b4.y; acc[3][2] += a3 * b4.z; acc[3][3] += a3 * b4.w;
    }
    __syncthreads();
  }
  float4 bv = *(const float4*)(bff + n0 + c0);
#pragma unroll
  for (int i = 0; i < 4; ++i) {
    int rg = m0 + r0 + i;
    if (rg < n) {
      int tok = idx[(g << 11) + rg];
      float gt = gateArr[b * Sn + tok];
      float* orow = out + ((size_t)(b * Sn + tok) << 10) + n0 + c0;
      *(float4*)orow = make_float4((acc[i][0] + bv.x) * gt, (acc[i][1] + bv.y) * gt,
                                   (acc[i][2] + bv.z) * gt, (acc[i][3] + bv.w) * gt);
    }
  }
}

extern "C" void kernel_launch(void* const* d_in, const int* in_sizes, int n_in,
                              void* d_out, int out_size, void* d_ws, size_t ws_size,
                              hipStream_t stream) {
  const float* x    = (const float*)d_in[0];
  const float* Wg   = (const float*)d_in[1];
  const float* Wqkv = (const float*)d_in[2];
  const float* Wff  = (const float*)d_in[3];
  const float* bff  = (const float*)d_in[4];
  const float* cosT = (const float*)d_in[5];
  const float* sinT = (const float*)d_in[6];
  float* out = (float*)d_out;

  size_t off = 0;
  auto carve = [&](size_t bytes) -> void* {
    void* p = (char*)d_ws + off;
    off += (bytes + 255) & ~(size_t)255;
    return p;
  };
  unsigned short* xh_hi  = (unsigned short*)carve((size_t)Bn * Sn * Dn * 2);
  unsigned short* xh_lo  = (unsigned short*)carve((size_t)Bn * Sn * Dn * 2);
  unsigned short* WqT_hi = (unsigned short*)carve((size_t)En * 384 * Dn * 2);
  unsigned short* WqT_lo = (unsigned short*)carve((size_t)En * 384 * Dn * 2);
  float* qkv     = (float*)carve((size_t)Bn * Sn * 384 * sizeof(float));
  float* ctx     = (float*)carve((size_t)Bn * Sn * HDn * sizeof(float));
  float* gateArr = (float*)carve((size_t)Bn * Sn * sizeof(float));
  int*   expertA = (int*)carve((size_t)Bn * Sn * sizeof(int));
  int*   idx     = (int*)carve((size_t)NG * Sn * sizeof(int));
  int*   cnt     = (int*)carve((size_t)NG * sizeof(int));
  (void)ws_size; (void)in_sizes; (void)n_in; (void)out_size;

  k_rope_gate<<<dim3(Bn * Sn), dim3(256), 0, stream>>>(x, Wg, cosT, sinT, xh_hi, xh_lo, expertA, gateArr);
  k_prep_w<<<dim3(16, 6, 8), dim3(256), 0, stream>>>(Wqkv, WqT_hi, WqT_lo);
  k_route<<<dim3(NG), dim3(256), 0, stream>>>(expertA, idx, cnt);
  k_qkv<<<dim3(Sn / 64, NG), dim3(256), 0, stream>>>(xh_hi, xh_lo, WqT_hi, WqT_lo, idx, cnt, qkv);
  k_attn<<<dim3(Sn / 32, NG), dim3(256), 0, stream>>>(qkv, idx, cnt, ctx);
  k_out<<<dim3(Sn / 32, NG, 8), dim3(256), 0, stream>>>(ctx, Wff, bff, idx, cnt, gateArr, out);
}

// Round 3
// 291.297 us; speedup vs baseline: 3.1487x; 2.5481x over previous
//
#include <hip/hip_runtime.h>
#include <math.h>

#define Bn 4
#define Sn 2048
#define Dn 1024
#define En 8
#define HDn 128
#define NG 32
#define MAXT 160

typedef __attribute__((ext_vector_type(8))) short bf16x8;
typedef __attribute__((ext_vector_type(4))) float f32x4;
typedef unsigned short u16;

__device__ __forceinline__ unsigned bf16_rn(float x) {
  unsigned u = __float_as_uint(x);
  return (u + 0x7fffu + ((u >> 16) & 1u)) >> 16;
}
__device__ __forceinline__ void bsplit(float x, unsigned& hi, unsigned& lo) {
  hi = bf16_rn(x);
  lo = bf16_rn(x - __uint_as_float(hi << 16));
}
__device__ __forceinline__ void gl16(const void* g, void* l) {
  __builtin_amdgcn_global_load_lds(
      (const __attribute__((address_space(1))) void*)g,
      (__attribute__((address_space(3))) void*)l, 16, 0, 0);
}
#define MFMA16(a, b, c) __builtin_amdgcn_mfma_f32_16x16x32_bf16((a), (b), (c), 0, 0, 0)

// ---------------- K1: RoPE + gating; emits xh as bf16 hi/lo ----------------
__global__ __launch_bounds__(256) void k_rope_gate(
    const float* __restrict__ x, const float* __restrict__ Wg,
    const float* __restrict__ cosT, const float* __restrict__ sinT,
    u16* __restrict__ xh_hi, u16* __restrict__ xh_lo,
    int* __restrict__ expertArr, float* __restrict__ gateArr)
{
  int bs = blockIdx.x;
  int s  = bs & (Sn - 1);
  const float* xrow = x + (size_t)bs * Dn;
  int t = threadIdx.x;
  int j = t << 2;
  int hbase = j & ~127;
  int jj = j & 127;
  float v0, v1, v2, v3;
  if (jj < 64) {
    const float* pe = xrow + hbase + 64 + jj;
    float a0 = pe[0], a1 = pe[1], a2 = pe[2], a3 = pe[3];
    int p0 = jj >> 1;
    float c0 = cosT[s * 32 + p0],     s0 = sinT[s * 32 + p0];
    float c1 = cosT[s * 32 + p0 + 1], s1 = sinT[s * 32 + p0 + 1];
    v0 = a0 * c0 - a1 * s0;
    v1 = a0 * s0 + a1 * c0;
    v2 = a2 * c1 - a3 * s1;
    v3 = a2 * s1 + a3 * c1;
  } else {
    const float* np = xrow + hbase + (jj - 64);
    v0 = np[0]; v1 = np[1]; v2 = np[2]; v3 = np[3];
  }
  unsigned h0,l0,h1,l1,h2,l2,h3,l3;
  bsplit(v0,h0,l0); bsplit(v1,h1,l1); bsplit(v2,h2,l2); bsplit(v3,h3,l3);
  *(ushort4*)(xh_hi + (size_t)bs * Dn + j) = make_ushort4((u16)h0,(u16)h1,(u16)h2,(u16)h3);
  *(ushort4*)(xh_lo + (size_t)bs * Dn + j) = make_ushort4((u16)l0,(u16)l1,(u16)l2,(u16)l3);

  float pl[En];
  const float* wr = Wg + (size_t)j * En;
#pragma unroll
  for (int e = 0; e < En; ++e)
    pl[e] = v0 * wr[e] + v1 * wr[En + e] + v2 * wr[2 * En + e] + v3 * wr[3 * En + e];
#pragma unroll
  for (int off = 1; off < 64; off <<= 1) {
#pragma unroll
    for (int e = 0; e < En; ++e) pl[e] += __shfl_xor(pl[e], off, 64);
  }
  __shared__ float red[4][En];
  int wv = t >> 6, ln = t & 63;
  if (ln == 0) {
#pragma unroll
    for (int e = 0; e < En; ++e) red[wv][e] = pl[e];
  }
  __syncthreads();
  if (t == 0) {
    float l[En];
    for (int e = 0; e < En; ++e) l[e] = red[0][e] + red[1][e] + red[2][e] + red[3][e];
    float m = l[0]; int be = 0;
    for (int e = 1; e < En; ++e) if (l[e] > m) { m = l[e]; be = e; }
    float ss = 0.f;
    for (int e = 0; e < En; ++e) ss += expf(l[e] - m);
    expertArr[bs] = be;
    gateArr[bs] = 1.0f / ss;
  }
}

// ------- K1b: generic transpose+split  W[e][K][N] -> [e][N][K] bf16 hi/lo -------
__global__ __launch_bounds__(256) void k_prep_w(
    const float* __restrict__ W, u16* __restrict__ hiT, u16* __restrict__ loT,
    int Kdim, int Ndim)
{
  int e = blockIdx.z, k0 = blockIdx.x << 6, c0 = blockIdx.y << 6;
  __shared__ float tile[64][65];
  int t = threadIdx.x;
  int r = t >> 4, cc = (t & 15) << 2;
  const float* src = W + ((size_t)e * Kdim + k0) * Ndim + c0;
#pragma unroll
  for (int i = 0; i < 4; ++i) {
    float4 v = *(const float4*)(src + (size_t)(r + i * 16) * Ndim + cc);
    tile[r + i * 16][cc + 0] = v.x; tile[r + i * 16][cc + 1] = v.y;
    tile[r + i * 16][cc + 2] = v.z; tile[r + i * 16][cc + 3] = v.w;
  }
  __syncthreads();
#pragma unroll
  for (int i = 0; i < 4; ++i) {
    int oc = (t >> 4) + i * 16;
    int ok = (t & 15) << 2;
    float v0 = tile[ok + 0][oc], v1 = tile[ok + 1][oc];
    float v2 = tile[ok + 2][oc], v3 = tile[ok + 3][oc];
    unsigned h0,l0,h1,l1,h2,l2,h3,l3;
    bsplit(v0,h0,l0); bsplit(v1,h1,l1); bsplit(v2,h2,l2); bsplit(v3,h3,l3);
    size_t o = ((size_t)e * Ndim + c0 + oc) * Kdim + k0 + ok;
    *(ushort4*)(hiT + o) = make_ushort4((u16)h0,(u16)h1,(u16)h2,(u16)h3);
    *(ushort4*)(loT + o) = make_ushort4((u16)l0,(u16)l1,(u16)l2,(u16)l3);
  }
}

// ---------------- K2: stable per-(b,e) token lists ----------------
__global__ __launch_bounds__(256) void k_route(
    const int* __restrict__ expertArr, int* __restrict__ idx, int* __restrict__ cnt)
{
  int g = blockIdx.x;
  int b = g >> 3, e = g & 7;
  int t = threadIdx.x;
  __shared__ int wtot[4];
  __shared__ int base;
  if (t == 0) base = 0;
  __syncthreads();
  for (int c = 0; c < Sn; c += 256) {
    int s = c + t;
    int pred = (expertArr[b * Sn + s] == e) ? 1 : 0;
    unsigned long long mask = __ballot(pred);
    int ln = t & 63, wv = t >> 6;
    int wpre = __popcll(mask & ((1ull << ln) - 1ull));
    if (ln == 63) wtot[wv] = wpre + pred;
    __syncthreads();
    int woff = 0;
    for (int w = 0; w < wv; ++w) woff += wtot[w];
    int tot = wtot[0] + wtot[1] + wtot[2] + wtot[3];
    if (pred) idx[(g << 11) + base + woff + wpre] = s;
    __syncthreads();
    if (t == 0) base += tot;
    __syncthreads();
  }
  if (t == 0) cnt[g] = base;
}

// ---------------- K2b: compact 64-row tile table ----------------
__global__ void k_tiles(const int* __restrict__ cnt, int* __restrict__ tileg,
                        int* __restrict__ tilem, int* __restrict__ ntile)
{
  if (threadIdx.x == 0 && blockIdx.x == 0) {
    int t = 0;
    for (int g = 0; g < NG; ++g) {
      int n = cnt[g];
      for (int m0 = 0; m0 < n && t < MAXT; m0 += 64) { tileg[t] = g; tilem[t] = m0; ++t; }
    }
    ntile[0] = t;
  }
}

// ------- K3: grouped QKV GEMM, LDS-pipelined MFMA bf16x3 (single K pass) -------
// BM=64, BN=64, BK=64; 4 waves 2x2 (each 32x32). LDS dbuf: [Ahi|Alo|Bhi|Blo] 8KB each.
__global__ __launch_bounds__(256) void k_qkv(
    const u16* __restrict__ xh_hi, const u16* __restrict__ xh_lo,
    const u16* __restrict__ WqT_hi, const u16* __restrict__ WqT_lo,
    const int* __restrict__ idx, const int* __restrict__ cnt,
    const int* __restrict__ tileg, const int* __restrict__ tilem,
    const int* __restrict__ ntile,
    float* __restrict__ qkv)
{
  extern __shared__ unsigned char LDS[];
  int tid = blockIdx.x;
  if (tid >= ntile[0]) return;
  int g = tileg[tid], m0 = tilem[tid];
  int n = cnt[g];
  int b = g >> 3, e = g & 7;
  const int* idxg = idx + (g << 11);
  int n0 = blockIdx.y << 6;
  int t = threadIdx.x;
  int wid = t >> 6, l = t & 63;
  int wr = wid >> 1, wc = wid & 1;
  int lc = l & 15, lq = l >> 4;

  // staging lane mapping: instr q covers rows q*8..q*8+8; lane i -> row q*8+(i>>3),
  // global k-slot ((i&7)^(row&7)) so that linear LDS dest == swizzled layout.
  int q0 = wid * 2, q1 = q0 + 1;
  int rl0 = q0 * 8 + (l >> 3), rl1 = q1 * 8 + (l >> 3);
  int kt0 = ((l & 7) ^ (rl0 & 7)) * 8;   // element offset of this lane's 16B slot
  int kt1 = ((l & 7) ^ (rl1 & 7)) * 8;
  int rg0 = m0 + rl0; rg0 = rg0 < n ? rg0 : n - 1;
  int rg1 = m0 + rl1; rg1 = rg1 < n ? rg1 : n - 1;
  size_t aoff0 = ((size_t)(b * Sn + idxg[rg0])) * Dn + kt0;
  size_t aoff1 = ((size_t)(b * Sn + idxg[rg1])) * Dn + kt1;
  size_t boff0 = ((size_t)e * 384 + n0 + rl0) * Dn + kt0;
  size_t boff1 = ((size_t)e * 384 + n0 + rl1) * Dn + kt1;
  int dq0 = q0 << 10, dq1 = q1 << 10;    // LDS byte base per instr (8 rows * 128B)

  f32x4 acc[2][2];
#pragma unroll
  for (int i = 0; i < 2; ++i)
#pragma unroll
    for (int j = 0; j < 2; ++j) acc[i][j] = (f32x4){0.f, 0.f, 0.f, 0.f};

  int rA0 = wr * 32 + lc, rA1 = rA0 + 16;   // A rows for frags fi=0,1
  int cB0 = wc * 32 + lc, cB1 = cB0 + 16;   // B cols for frags fj=0,1
  int sw = lc & 7;                           // (rA&7)==(cB&7)==lc&7

#define STAGE(bufb, k0)                                                      \
  do {                                                                       \
    unsigned bb = (bufb);                                                    \
    gl16(xh_hi + aoff0 + (k0), LDS + bb + dq0);                              \
    gl16(xh_hi + aoff1 + (k0), LDS + bb + dq1);                              \
    gl16(xh_lo + aoff0 + (k0), LDS + bb + 8192 + dq0);                       \
    gl16(xh_lo + aoff1 + (k0), LDS + bb + 8192 + dq1);                       \
    gl16(WqT_hi + boff0 + (k0), LDS + bb + 16384 + dq0);                     \
    gl16(WqT_hi + boff1 + (k0), LDS + bb + 16384 + dq1);                     \
    gl16(WqT_lo + boff0 + (k0), LDS + bb + 24576 + dq0);                     \
    gl16(WqT_lo + boff1 + (k0), LDS + bb + 24576 + dq1);                     \
  } while (0)

  STAGE(0, 0);
  __syncthreads();
  for (int tt = 0; tt < 16; ++tt) {
    unsigned cur = (tt & 1) ? 32768u : 0u;
    if (tt < 15) STAGE(cur ^ 32768u, (tt + 1) * 64);
#pragma unroll
    for (int ks = 0; ks < 2; ++ks) {
      int sl = ks * 4 + lq;
      int sx = (sl ^ sw) << 4;
      int a0b = cur + rA0 * 128 + sx;
      int a1b = cur + rA1 * 128 + sx;
      int b0b = cur + 16384 + cB0 * 128 + sx;
      int b1b = cur + 16384 + cB1 * 128 + sx;
      bf16x8 ah0 = *(const bf16x8*)(LDS + a0b);
      bf16x8 ah1 = *(const bf16x8*)(LDS + a1b);
      bf16x8 al0 = *(const bf16x8*)(LDS + a0b + 8192);
      bf16x8 al1 = *(const bf16x8*)(LDS + a1b + 8192);
      bf16x8 bh0 = *(const bf16x8*)(LDS + b0b);
      bf16x8 bh1 = *(const bf16x8*)(LDS + b1b);
      bf16x8 bl0 = *(const bf16x8*)(LDS + b0b + 8192);
      bf16x8 bl1 = *(const bf16x8*)(LDS + b1b + 8192);
      acc[0][0] = MFMA16(ah0, bh0, acc[0][0]);
      acc[0][1] = MFMA16(ah0, bh1, acc[0][1]);
      acc[1][0] = MFMA16(ah1, bh0, acc[1][0]);
      acc[1][1] = MFMA16(ah1, bh1, acc[1][1]);
      acc[0][0] = MFMA16(al0, bh0, acc[0][0]);
      acc[0][1] = MFMA16(al0, bh1, acc[0][1]);
      acc[1][0] = MFMA16(al1, bh0, acc[1][0]);
      acc[1][1] = MFMA16(al1, bh1, acc[1][1]);
      acc[0][0] = MFMA16(ah0, bl0, acc[0][0]);
      acc[0][1] = MFMA16(ah0, bl1, acc[0][1]);
      acc[1][0] = MFMA16(ah1, bl0, acc[1][0]);
      acc[1][1] = MFMA16(ah1, bl1, acc[1][1]);
    }
    __syncthreads();
  }
#undef STAGE

#pragma unroll
  for (int fi = 0; fi < 2; ++fi) {
#pragma unroll
    for (int rr = 0; rr < 4; ++rr) {
      int rg = m0 + wr * 32 + fi * 16 + lq * 4 + rr;
      if (rg < n) {
        int tok = idxg[rg];
        float* orow = qkv + (size_t)(b * Sn + tok) * 384 + n0 + wc * 32 + lc;
        orow[0]  = acc[fi][0][rr];
        orow[16] = acc[fi][1][rr];
      }
    }
  }
}

// ---------------- K4: grouped flash attention; emits ctx bf16 hi/lo ----------------
__global__ __launch_bounds__(256) void k_attn(
    const float* __restrict__ qkv, const int* __restrict__ idx,
    const int* __restrict__ cnt, u16* __restrict__ ctx_hi, u16* __restrict__ ctx_lo)
{
  int g = blockIdx.y;
  int n = cnt[g];
  int m0 = blockIdx.x << 5;
  if (m0 >= n) return;
  int b = g >> 3;
  __shared__ float Qs[32][132];
  __shared__ float Ks[32][132];
  __shared__ float Vs[32][132];
  __shared__ float Ps[32][36];
  int t = threadIdx.x;
  {
    int q = t >> 3, c0 = (t & 7) << 2;
    int rg = m0 + q;
    bool v = (rg < n);
    const float* qrow = v ? (qkv + (size_t)(b * Sn + idx[(g << 11) + rg]) * 384) : qkv;
#pragma unroll
    for (int jt = 0; jt < 4; ++jt) {
      int c = c0 + (jt << 5);
      float4 vq = v ? *(const float4*)(qrow + c) : make_float4(0.f, 0.f, 0.f, 0.f);
      *(float4*)(&Qs[q][c]) = vq;
    }
  }
  int q = t >> 3, kk = t & 7;
  float m_r = -1e30f, l_r = 0.f;
  float acc[16];
#pragma unroll
  for (int i = 0; i < 16; ++i) acc[i] = 0.f;
  const float scale = 0.08838834764831845f;

  for (int kc = 0; kc < n; kc += 32) {
    {
      int kr = t >> 3, c0 = (t & 7) << 2;
      int kg = kc + kr;
      bool v = (kg < n);
      const float* krow = v ? (qkv + (size_t)(b * Sn + idx[(g << 11) + kg]) * 384 + 128) : qkv;
      int sw = (kr >> 2) & 7;
#pragma unroll
      for (int jt = 0; jt < 4; ++jt) {
        int c = c0 + (jt << 5);
        float4 kv = v ? *(const float4*)(krow + c) : make_float4(0.f, 0.f, 0.f, 0.f);
        int cb = c >> 2;
        *(float4*)(&Ks[kr][(cb ^ sw) << 2]) = kv;
        float4 vv = v ? *(const float4*)(krow + 128 + c) : make_float4(0.f, 0.f, 0.f, 0.f);
        *(float4*)(&Vs[kr][c]) = vv;
      }
    }
    __syncthreads();
    float sv[4] = {0.f, 0.f, 0.f, 0.f};
#pragma unroll
    for (int d4 = 0; d4 < 128; d4 += 4) {
      float4 qv = *(const float4*)(&Qs[q][d4]);
      int cbs = ((d4 >> 2) ^ kk) << 2;
#pragma unroll
      for (int jj = 0; jj < 4; ++jj) {
        float4 kv = *(const float4*)(&Ks[kk * 4 + jj][cbs]);
        sv[jj] += qv.x * kv.x + qv.y * kv.y + qv.z * kv.z + qv.w * kv.w;
      }
    }
    float mloc = -1e30f;
#pragma unroll
    for (int jj = 0; jj < 4; ++jj) {
      int kg = kc + kk * 4 + jj;
      sv[jj] = (kg < n) ? sv[jj] * scale : -1e30f;
      mloc = fmaxf(mloc, sv[jj]);
    }
    mloc = fmaxf(mloc, __shfl_xor(mloc, 1, 64));
    mloc = fmaxf(mloc, __shfl_xor(mloc, 2, 64));
    mloc = fmaxf(mloc, __shfl_xor(mloc, 4, 64));
    float m_new = fmaxf(m_r, mloc);
    float corr = expf(m_r - m_new);
    float rs = 0.f;
#pragma unroll
    for (int jj = 0; jj < 4; ++jj) {
      float p = expf(sv[jj] - m_new);
      Ps[q][kk * 4 + jj] = p;
      rs += p;
    }
    rs += __shfl_xor(rs, 1, 64);
    rs += __shfl_xor(rs, 2, 64);
    rs += __shfl_xor(rs, 4, 64);
    l_r = l_r * corr + rs;
    m_r = m_new;
#pragma unroll
    for (int i = 0; i < 16; ++i) acc[i] *= corr;
    __syncthreads();
#pragma unroll
    for (int key = 0; key < 32; ++key) {
      float pv = Ps[q][key];
      const float* vr = &Vs[key][kk << 4];
#pragma unroll
      for (int i4 = 0; i4 < 4; ++i4) {
        float4 vv = *(const float4*)(vr + (i4 << 2));
        acc[i4 * 4 + 0] += pv * vv.x;
        acc[i4 * 4 + 1] += pv * vv.y;
        acc[i4 * 4 + 2] += pv * vv.z;
        acc[i4 * 4 + 3] += pv * vv.w;
      }
    }
    __syncthreads();
  }
  int rg = m0 + q;
  if (rg < n) {
    int tok = idx[(g << 11) + rg];
    float inv = 1.0f / l_r;
    size_t base = ((size_t)(b * Sn + tok)) * HDn + (kk << 4);
#pragma unroll
    for (int i4 = 0; i4 < 4; ++i4) {
      unsigned h[4], lo[4];
#pragma unroll
      for (int j = 0; j < 4; ++j) bsplit(acc[i4 * 4 + j] * inv, h[j], lo[j]);
      *(ushort4*)(ctx_hi + base + (i4 << 2)) = make_ushort4((u16)h[0],(u16)h[1],(u16)h[2],(u16)h[3]);
      *(ushort4*)(ctx_lo + base + (i4 << 2)) = make_ushort4((u16)lo[0],(u16)lo[1],(u16)lo[2],(u16)lo[3]);
    }
  }
}

// ---------------- K5: out projection via MFMA bf16x3 + gate + scatter ----------------
// 4 waves, each 64 rows x 64 cols; K=128 direct-from-global (cache-resident weights).
__global__ __launch_bounds__(256) void k_out(
    const u16* __restrict__ ctx_hi, const u16* __restrict__ ctx_lo,
    const u16* __restrict__ WfT_hi, const u16* __restrict__ WfT_lo,
    const float* __restrict__ bff,
    const int* __restrict__ idx, const int* __restrict__ cnt,
    const int* __restrict__ tileg, const int* __restrict__ tilem,
    const int* __restrict__ ntile,
    const float* __restrict__ gateArr,
    float* __restrict__ out)
{
  int tid = blockIdx.x;
  if (tid >= ntile[0]) return;
  int g = tileg[tid], m0 = tilem[tid];
  int n = cnt[g];
  int b = g >> 3, e = g & 7;
  const int* idxg = idx + (g << 11);
  int t = threadIdx.x, wid = t >> 6, l = t & 63;
  int lc = l & 15, lq = l >> 4;
  int n0 = blockIdx.y * 256 + wid * 64;

  f32x4 acc[4][4];
#pragma unroll
  for (int i = 0; i < 4; ++i)
#pragma unroll
    for (int j = 0; j < 4; ++j) acc[i][j] = (f32x4){0.f, 0.f, 0.f, 0.f};

  size_t aoff[4];
#pragma unroll
  for (int fi = 0; fi < 4; ++fi) {
    int rg = m0 + fi * 16 + lc; rg = rg < n ? rg : n - 1;
    aoff[fi] = ((size_t)(b * Sn + idxg[rg])) * HDn + lq * 8;
  }
  size_t boff[4];
#pragma unroll
  for (int fj = 0; fj < 4; ++fj)
    boff[fj] = ((size_t)e * Dn + n0 + fj * 16 + lc) * HDn + lq * 8;

#pragma unroll
  for (int ks = 0; ks < 4; ++ks) {
    int ko = ks * 32;
    bf16x8 ah[4], al[4], bh[4], bl[4];
#pragma unroll
    for (int fi = 0; fi < 4; ++fi) {
      ah[fi] = *(const bf16x8*)(ctx_hi + aoff[fi] + ko);
      al[fi] = *(const bf16x8*)(ctx_lo + aoff[fi] + ko);
    }
#pragma unroll
    for (int fj = 0; fj < 4; ++fj) {
      bh[fj] = *(const bf16x8*)(WfT_hi + boff[fj] + ko);
      bl[fj] = *(const bf16x8*)(WfT_lo + boff[fj] + ko);
    }
#pragma unroll
    for (int fi = 0; fi < 4; ++fi)
#pragma unroll
      for (int fj = 0; fj < 4; ++fj) {
        acc[fi][fj] = MFMA16(ah[fi], bh[fj], acc[fi][fj]);
        acc[fi][fj] = MFMA16(al[fi], bh[fj], acc[fi][fj]);
        acc[fi][fj] = MFMA16(ah[fi], bl[fj], acc[fi][fj]);
      }
  }

  float bv[4];
#pragma unroll
  for (int fj = 0; fj < 4; ++fj) bv[fj] = bff[n0 + fj * 16 + lc];

#pragma unroll
  for (int fi = 0; fi < 4; ++fi) {
#pragma unroll
    for (int rr = 0; rr < 4; ++rr) {
      int rg = m0 + fi * 16 + lq * 4 + rr;
      if (rg < n) {
        int tok = idxg[rg];
        float gt = gateArr[b * Sn + tok];
        float* orow = out + ((size_t)(b * Sn + tok)) * Dn + n0 + lc;
#pragma unroll
        for (int fj = 0; fj < 4; ++fj)
          orow[fj * 16] = (acc[fi][fj][rr] + bv[fj]) * gt;
      }
    }
  }
}

extern "C" void kernel_launch(void* const* d_in, const int* in_sizes, int n_in,
                              void* d_out, int out_size, void* d_ws, size_t ws_size,
                              hipStream_t stream) {
  const float* x    = (const float*)d_in[0];
  const float* Wg   = (const float*)d_in[1];
  const float* Wqkv = (const float*)d_in[2];
  const float* Wff  = (const float*)d_in[3];
  const float* bff  = (const float*)d_in[4];
  const float* cosT = (const float*)d_in[5];
  const float* sinT = (const float*)d_in[6];
  float* out = (float*)d_out;

  size_t off = 0;
  auto carve = [&](size_t bytes) -> void* {
    void* p = (char*)d_ws + off;
    off += (bytes + 255) & ~(size_t)255;
    return p;
  };
  u16* xh_hi  = (u16*)carve((size_t)Bn * Sn * Dn * 2);
  u16* xh_lo  = (u16*)carve((size_t)Bn * Sn * Dn * 2);
  u16* WqT_hi = (u16*)carve((size_t)En * 384 * Dn * 2);
  u16* WqT_lo = (u16*)carve((size_t)En * 384 * Dn * 2);
  u16* WfT_hi = (u16*)carve((size_t)En * Dn * HDn * 2);
  u16* WfT_lo = (u16*)carve((size_t)En * Dn * HDn * 2);
  float* qkv     = (float*)carve((size_t)Bn * Sn * 384 * sizeof(float));
  u16* ctx_hi    = (u16*)carve((size_t)Bn * Sn * HDn * 2);
  u16* ctx_lo    = (u16*)carve((size_t)Bn * Sn * HDn * 2);
  float* gateArr = (float*)carve((size_t)Bn * Sn * sizeof(float));
  int*   expertA = (int*)carve((size_t)Bn * Sn * sizeof(int));
  int*   idx     = (int*)carve((size_t)NG * Sn * sizeof(int));
  int*   cnt     = (int*)carve((size_t)NG * sizeof(int));
  int*   tileg   = (int*)carve((size_t)MAXT * sizeof(int));
  int*   tilem   = (int*)carve((size_t)MAXT * sizeof(int));
  int*   ntile   = (int*)carve(256);
  (void)ws_size; (void)in_sizes; (void)n_in; (void)out_size;

  k_rope_gate<<<dim3(Bn * Sn), dim3(256), 0, stream>>>(x, Wg, cosT, sinT, xh_hi, xh_lo, expertA, gateArr);
  k_prep_w<<<dim3(16, 6, 8), dim3(256), 0, stream>>>(Wqkv, WqT_hi, WqT_lo, Dn, 384);
  k_prep_w<<<dim3(2, 16, 8), dim3(256), 0, stream>>>(Wff, WfT_hi, WfT_lo, HDn, Dn);
  k_route<<<dim3(NG), dim3(256), 0, stream>>>(expertA, idx, cnt);
  k_tiles<<<dim3(1), dim3(64), 0, stream>>>(cnt, tileg, tilem, ntile);
  k_qkv<<<dim3(MAXT, 6), dim3(256), 65536, stream>>>(xh_hi, xh_lo, WqT_hi, WqT_lo, idx, cnt, tileg, tilem, ntile, qkv);
  k_attn<<<dim3(Sn / 32, NG), dim3(256), 0, stream>>>(qkv, idx, cnt, ctx_hi, ctx_lo);
  k_out<<<dim3(MAXT, 4), dim3(256), 0, stream>>>(ctx_hi, ctx_lo, WfT_hi, WfT_lo, bff, idx, cnt, tileg, tilem, ntile, gateArr, out);
}

// Round 4
// 184.988 us; speedup vs baseline: 4.9581x; 1.5747x over previous
//
#include <hip/hip_runtime.h>
#include <math.h>

#define Bn 4
#define Sn 2048
#define Dn 1024
#define En 8
#define HDn 128
#define NG 32
#define MAXT 160
#define MAXN 1024   // max tokens per (b,e) group (n ~ 256 +- 15; 1024 is >> any tail)

typedef __attribute__((ext_vector_type(8))) short bf16x8;
typedef __attribute__((ext_vector_type(4))) float f32x4;
typedef unsigned short u16;

__device__ __forceinline__ unsigned bf16_rn(float x) {
  unsigned u = __float_as_uint(x);
  return (u + 0x7fffu + ((u >> 16) & 1u)) >> 16;
}
__device__ __forceinline__ void bsplit(float x, unsigned& hi, unsigned& lo) {
  hi = bf16_rn(x);
  lo = bf16_rn(x - __uint_as_float(hi << 16));
}
__device__ __forceinline__ void gl16(const void* g, void* l) {
  __builtin_amdgcn_global_load_lds(
      (const __attribute__((address_space(1))) void*)g,
      (__attribute__((address_space(3))) void*)l, 16, 0, 0);
}
#define MFMA16(a, b, c) __builtin_amdgcn_mfma_f32_16x16x32_bf16((a), (b), (c), 0, 0, 0)

// ---------------- K1: RoPE + gating; emits xh as bf16 hi/lo ----------------
__global__ __launch_bounds__(256) void k_rope_gate(
    const float* __restrict__ x, const float* __restrict__ Wg,
    const float* __restrict__ cosT, const float* __restrict__ sinT,
    u16* __restrict__ xh_hi, u16* __restrict__ xh_lo,
    int* __restrict__ expertArr, float* __restrict__ gateArr)
{
  int bs = blockIdx.x;
  int s  = bs & (Sn - 1);
  const float* xrow = x + (size_t)bs * Dn;
  int t = threadIdx.x;
  int j = t << 2;
  int hbase = j & ~127;
  int jj = j & 127;
  float v0, v1, v2, v3;
  if (jj < 64) {
    const float* pe = xrow + hbase + 64 + jj;
    float a0 = pe[0], a1 = pe[1], a2 = pe[2], a3 = pe[3];
    int p0 = jj >> 1;
    float c0 = cosT[s * 32 + p0],     s0 = sinT[s * 32 + p0];
    float c1 = cosT[s * 32 + p0 + 1], s1 = sinT[s * 32 + p0 + 1];
    v0 = a0 * c0 - a1 * s0;
    v1 = a0 * s0 + a1 * c0;
    v2 = a2 * c1 - a3 * s1;
    v3 = a2 * s1 + a3 * c1;
  } else {
    const float* np = xrow + hbase + (jj - 64);
    v0 = np[0]; v1 = np[1]; v2 = np[2]; v3 = np[3];
  }
  unsigned h0,l0,h1,l1,h2,l2,h3,l3;
  bsplit(v0,h0,l0); bsplit(v1,h1,l1); bsplit(v2,h2,l2); bsplit(v3,h3,l3);
  *(ushort4*)(xh_hi + (size_t)bs * Dn + j) = make_ushort4((u16)h0,(u16)h1,(u16)h2,(u16)h3);
  *(ushort4*)(xh_lo + (size_t)bs * Dn + j) = make_ushort4((u16)l0,(u16)l1,(u16)l2,(u16)l3);

  float pl[En];
  const float* wr = Wg + (size_t)j * En;
#pragma unroll
  for (int e = 0; e < En; ++e)
    pl[e] = v0 * wr[e] + v1 * wr[En + e] + v2 * wr[2 * En + e] + v3 * wr[3 * En + e];
#pragma unroll
  for (int off = 1; off < 64; off <<= 1) {
#pragma unroll
    for (int e = 0; e < En; ++e) pl[e] += __shfl_xor(pl[e], off, 64);
  }
  __shared__ float red[4][En];
  int wv = t >> 6, ln = t & 63;
  if (ln == 0) {
#pragma unroll
    for (int e = 0; e < En; ++e) red[wv][e] = pl[e];
  }
  __syncthreads();
  if (t == 0) {
    float l[En];
    for (int e = 0; e < En; ++e) l[e] = red[0][e] + red[1][e] + red[2][e] + red[3][e];
    float m = l[0]; int be = 0;
    for (int e = 1; e < En; ++e) if (l[e] > m) { m = l[e]; be = e; }
    float ss = 0.f;
    for (int e = 0; e < En; ++e) ss += expf(l[e] - m);
    expertArr[bs] = be;
    gateArr[bs] = 1.0f / ss;
  }
}

// ------- K1b: generic transpose+split  W[e][K][N] -> [e][N][K] bf16 hi/lo -------
__global__ __launch_bounds__(256) void k_prep_w(
    const float* __restrict__ W, u16* __restrict__ hiT, u16* __restrict__ loT,
    int Kdim, int Ndim)
{
  int e = blockIdx.z, k0 = blockIdx.x << 6, c0 = blockIdx.y << 6;
  __shared__ float tile[64][65];
  int t = threadIdx.x;
  int r = t >> 4, cc = (t & 15) << 2;
  const float* src = W + ((size_t)e * Kdim + k0) * Ndim + c0;
#pragma unroll
  for (int i = 0; i < 4; ++i) {
    float4 v = *(const float4*)(src + (size_t)(r + i * 16) * Ndim + cc);
    tile[r + i * 16][cc + 0] = v.x; tile[r + i * 16][cc + 1] = v.y;
    tile[r + i * 16][cc + 2] = v.z; tile[r + i * 16][cc + 3] = v.w;
  }
  __syncthreads();
#pragma unroll
  for (int i = 0; i < 4; ++i) {
    int oc = (t >> 4) + i * 16;
    int ok = (t & 15) << 2;
    float v0 = tile[ok + 0][oc], v1 = tile[ok + 1][oc];
    float v2 = tile[ok + 2][oc], v3 = tile[ok + 3][oc];
    unsigned h0,l0,h1,l1,h2,l2,h3,l3;
    bsplit(v0,h0,l0); bsplit(v1,h1,l1); bsplit(v2,h2,l2); bsplit(v3,h3,l3);
    size_t o = ((size_t)e * Ndim + c0 + oc) * Kdim + k0 + ok;
    *(ushort4*)(hiT + o) = make_ushort4((u16)h0,(u16)h1,(u16)h2,(u16)h3);
    *(ushort4*)(loT + o) = make_ushort4((u16)l0,(u16)l1,(u16)l2,(u16)l3);
  }
}

// ---------------- K2: stable per-(b,e) token lists ----------------
__global__ __launch_bounds__(256) void k_route(
    const int* __restrict__ expertArr, int* __restrict__ idx, int* __restrict__ cnt)
{
  int g = blockIdx.x;
  int b = g >> 3, e = g & 7;
  int t = threadIdx.x;
  __shared__ int wtot[4];
  __shared__ int base;
  if (t == 0) base = 0;
  __syncthreads();
  for (int c = 0; c < Sn; c += 256) {
    int s = c + t;
    int pred = (expertArr[b * Sn + s] == e) ? 1 : 0;
    unsigned long long mask = __ballot(pred);
    int ln = t & 63, wv = t >> 6;
    int wpre = __popcll(mask & ((1ull << ln) - 1ull));
    if (ln == 63) wtot[wv] = wpre + pred;
    __syncthreads();
    int woff = 0;
    for (int w = 0; w < wv; ++w) woff += wtot[w];
    int tot = wtot[0] + wtot[1] + wtot[2] + wtot[3];
    if (pred) idx[(g << 11) + base + woff + wpre] = s;
    __syncthreads();
    if (t == 0) base += tot;
    __syncthreads();
  }
  if (t == 0) cnt[g] = base;
}

// ---------------- K2b: compact 64-row tile table ----------------
__global__ void k_tiles(const int* __restrict__ cnt, int* __restrict__ tileg,
                        int* __restrict__ tilem, int* __restrict__ ntile)
{
  if (threadIdx.x == 0 && blockIdx.x == 0) {
    int t = 0;
    for (int g = 0; g < NG; ++g) {
      int n = cnt[g];
      for (int m0 = 0; m0 < n && t < MAXT; m0 += 64) { tileg[t] = g; tilem[t] = m0; ++t; }
    }
    ntile[0] = t;
  }
}

// ------- K3: grouped QKV GEMM, LDS-pipelined MFMA bf16x3 (single K pass) -------
// BM=64, BN=64, BK=64; 4 waves 2x2 (each 32x32). LDS dbuf: [Ahi|Alo|Bhi|Blo] 8KB each.
// Output: Q,K cols -> qkv_hi/lo [tok][384]; V cols -> vT_hi/lo [g][d=128][MAXN].
__global__ __launch_bounds__(256) void k_qkv(
    const u16* __restrict__ xh_hi, const u16* __restrict__ xh_lo,
    const u16* __restrict__ WqT_hi, const u16* __restrict__ WqT_lo,
    const int* __restrict__ idx, const int* __restrict__ cnt,
    const int* __restrict__ tileg, const int* __restrict__ tilem,
    const int* __restrict__ ntile,
    u16* __restrict__ qkv_hi, u16* __restrict__ qkv_lo,
    u16* __restrict__ vT_hi, u16* __restrict__ vT_lo)
{
  extern __shared__ unsigned char LDS[];
  int tid = blockIdx.x;
  if (tid >= ntile[0]) return;
  int g = tileg[tid], m0 = tilem[tid];
  int n = cnt[g];
  int b = g >> 3, e = g & 7;
  const int* idxg = idx + (g << 11);
  int n0 = blockIdx.y << 6;
  int t = threadIdx.x;
  int wid = t >> 6, l = t & 63;
  int wr = wid >> 1, wc = wid & 1;
  int lc = l & 15, lq = l >> 4;

  int q0 = wid * 2, q1 = q0 + 1;
  int rl0 = q0 * 8 + (l >> 3), rl1 = q1 * 8 + (l >> 3);
  int kt0 = ((l & 7) ^ (rl0 & 7)) * 8;
  int kt1 = ((l & 7) ^ (rl1 & 7)) * 8;
  int rg0 = m0 + rl0; rg0 = rg0 < n ? rg0 : n - 1;
  int rg1 = m0 + rl1; rg1 = rg1 < n ? rg1 : n - 1;
  size_t aoff0 = ((size_t)(b * Sn + idxg[rg0])) * Dn + kt0;
  size_t aoff1 = ((size_t)(b * Sn + idxg[rg1])) * Dn + kt1;
  size_t boff0 = ((size_t)e * 384 + n0 + rl0) * Dn + kt0;
  size_t boff1 = ((size_t)e * 384 + n0 + rl1) * Dn + kt1;
  int dq0 = q0 << 10, dq1 = q1 << 10;

  f32x4 acc[2][2];
#pragma unroll
  for (int i = 0; i < 2; ++i)
#pragma unroll
    for (int j = 0; j < 2; ++j) acc[i][j] = (f32x4){0.f, 0.f, 0.f, 0.f};

  int rA0 = wr * 32 + lc, rA1 = rA0 + 16;
  int cB0 = wc * 32 + lc, cB1 = cB0 + 16;
  int sw = lc & 7;

#define STAGE(bufb, k0)                                                      \
  do {                                                                       \
    unsigned bb = (bufb);                                                    \
    gl16(xh_hi + aoff0 + (k0), LDS + bb + dq0);                              \
    gl16(xh_hi + aoff1 + (k0), LDS + bb + dq1);                              \
    gl16(xh_lo + aoff0 + (k0), LDS + bb + 8192 + dq0);                       \
    gl16(xh_lo + aoff1 + (k0), LDS + bb + 8192 + dq1);                       \
    gl16(WqT_hi + boff0 + (k0), LDS + bb + 16384 + dq0);                     \
    gl16(WqT_hi + boff1 + (k0), LDS + bb + 16384 + dq1);                     \
    gl16(WqT_lo + boff0 + (k0), LDS + bb + 24576 + dq0);                     \
    gl16(WqT_lo + boff1 + (k0), LDS + bb + 24576 + dq1);                     \
  } while (0)

  STAGE(0, 0);
  __syncthreads();
  for (int tt = 0; tt < 16; ++tt) {
    unsigned cur = (tt & 1) ? 32768u : 0u;
    if (tt < 15) STAGE(cur ^ 32768u, (tt + 1) * 64);
#pragma unroll
    for (int ks = 0; ks < 2; ++ks) {
      int sl = ks * 4 + lq;
      int sx = (sl ^ sw) << 4;
      int a0b = cur + rA0 * 128 + sx;
      int a1b = cur + rA1 * 128 + sx;
      int b0b = cur + 16384 + cB0 * 128 + sx;
      int b1b = cur + 16384 + cB1 * 128 + sx;
      bf16x8 ah0 = *(const bf16x8*)(LDS + a0b);
      bf16x8 ah1 = *(const bf16x8*)(LDS + a1b);
      bf16x8 al0 = *(const bf16x8*)(LDS + a0b + 8192);
      bf16x8 al1 = *(const bf16x8*)(LDS + a1b + 8192);
      bf16x8 bh0 = *(const bf16x8*)(LDS + b0b);
      bf16x8 bh1 = *(const bf16x8*)(LDS + b1b);
      bf16x8 bl0 = *(const bf16x8*)(LDS + b0b + 8192);
      bf16x8 bl1 = *(const bf16x8*)(LDS + b1b + 8192);
      acc[0][0] = MFMA16(ah0, bh0, acc[0][0]);
      acc[0][1] = MFMA16(ah0, bh1, acc[0][1]);
      acc[1][0] = MFMA16(ah1, bh0, acc[1][0]);
      acc[1][1] = MFMA16(ah1, bh1, acc[1][1]);
      acc[0][0] = MFMA16(al0, bh0, acc[0][0]);
      acc[0][1] = MFMA16(al0, bh1, acc[0][1]);
      acc[1][0] = MFMA16(al1, bh0, acc[1][0]);
      acc[1][1] = MFMA16(al1, bh1, acc[1][1]);
      acc[0][0] = MFMA16(ah0, bl0, acc[0][0]);
      acc[0][1] = MFMA16(ah0, bl1, acc[0][1]);
      acc[1][0] = MFMA16(ah1, bl0, acc[1][0]);
      acc[1][1] = MFMA16(ah1, bl1, acc[1][1]);
    }
    __syncthreads();
  }
#undef STAGE

#pragma unroll
  for (int fi = 0; fi < 2; ++fi) {
#pragma unroll
    for (int rr = 0; rr < 4; ++rr) {
      int rg = m0 + wr * 32 + fi * 16 + lq * 4 + rr;
      if (rg < n) {
        int tok = idxg[rg];
#pragma unroll
        for (int fj = 0; fj < 2; ++fj) {
          int col = n0 + wc * 32 + fj * 16 + lc;
          unsigned h, lo2;
          bsplit(acc[fi][fj][rr], h, lo2);
          if (col < 256) {
            size_t o = (size_t)(b * Sn + tok) * 384 + col;
            qkv_hi[o] = (u16)h; qkv_lo[o] = (u16)lo2;
          } else {
            size_t o = ((size_t)g * HDn + (col - 256)) * MAXN + rg;
            vT_hi[o] = (u16)h; vT_lo[o] = (u16)lo2;
          }
        }
      }
    }
  }
}

// ------- K4: grouped flash attention via MFMA bf16x3 -------
// 64 q-rows/block (4 waves x 16), K-tiles of 64 keys double-buffered in LDS,
// V read direct-from-global (vT, L2-resident), P transposed through
// wave-private swizzled LDS. Emits ctx as bf16 hi/lo.
__global__ __launch_bounds__(256) void k_attn(
    const u16* __restrict__ qkv_hi, const u16* __restrict__ qkv_lo,
    const u16* __restrict__ vT_hi, const u16* __restrict__ vT_lo,
    const int* __restrict__ idx, const int* __restrict__ cnt,
    const int* __restrict__ tileg, const int* __restrict__ tilem,
    const int* __restrict__ ntile,
    u16* __restrict__ ctx_hi, u16* __restrict__ ctx_lo)
{
  extern __shared__ unsigned char LDS[];
  int tid = blockIdx.x;
  if (tid >= ntile[0]) return;
  int g = tileg[tid], m0 = tilem[tid];
  int n = cnt[g];
  int b = g >> 3;
  const int* idxg = idx + (g << 11);
  int t = threadIdx.x, wid = t >> 6, l = t & 63;
  int lc = l & 15, lq = l >> 4;
  const float scale = 0.08838834764831845f;   // 1/sqrt(128)

  // ---- Q fragments in registers (A-operand: row = lc, k-slice = lq*8) ----
  int qrg = m0 + wid * 16 + lc; qrg = qrg < n ? qrg : n - 1;
  size_t qoff = (size_t)(b * Sn + idxg[qrg]) * 384 + lq * 8;
  bf16x8 Qhi[4], Qlo[4];
#pragma unroll
  for (int ks = 0; ks < 4; ++ks) {
    Qhi[ks] = *(const bf16x8*)(qkv_hi + qoff + ks * 32);
    Qlo[ks] = *(const bf16x8*)(qkv_lo + qoff + ks * 32);
  }

  f32x4 acc[8];
#pragma unroll
  for (int i = 0; i < 8; ++i) acc[i] = (f32x4){0.f, 0.f, 0.f, 0.f};
  float m_r[4] = {-1e30f, -1e30f, -1e30f, -1e30f};
  float l_r[4] = {0.f, 0.f, 0.f, 0.f};

  // V base (B-operand: col d = df*16+lc, k-slice = keys lq*8)
  size_t vbase = ((size_t)g * HDn + lc) * MAXN + lq * 8;
  unsigned pbase = 65536u + wid * 4096u;   // wave-private P region (hi; lo at +2048)

  // K staging: 16 chunks/array of 4 rows (256B each); wave stages chunks wid*4..+3.
  // lane l -> row c*4 + lq, slot (l&15); pre-swizzled source slot = lc ^ ((c&1)*4 | lq).
#define STAGEK(bufb, kc)                                                     \
  do {                                                                       \
    unsigned bb = (bufb);                                                    \
    for (int j = 0; j < 4; ++j) {                                            \
      int c = wid * 4 + j;                                                   \
      int row = (kc) + c * 4 + lq;                                           \
      int rg = row < n ? row : n - 1;                                        \
      int srcslot = lc ^ (((c & 1) << 2) | lq);                              \
      size_t soff = (size_t)(b * Sn + idxg[rg]) * 384 + 128 + srcslot * 8;   \
      gl16(qkv_hi + soff, LDS + bb + c * 1024);                              \
      gl16(qkv_lo + soff, LDS + bb + 16384 + c * 1024);                      \
    }                                                                        \
  } while (0)

  int nt = (n + 63) >> 6;
  STAGEK(0, 0);
  __syncthreads();

  for (int tt = 0; tt < nt; ++tt) {
    unsigned cur = (tt & 1) ? 32768u : 0u;
    if (tt + 1 < nt) STAGEK(cur ^ 32768u, (tt + 1) * 64);
    int kc = tt * 64;

    // ---- S = Q K^T (bf16x3), frags: row q = lq*4+r, col key = kf*16+lc ----
    f32x4 Sf[4];
#pragma unroll
    for (int kf = 0; kf < 4; ++kf) Sf[kf] = (f32x4){0.f, 0.f, 0.f, 0.f};
#pragma unroll
    for (int ks = 0; ks < 4; ++ks) {
#pragma unroll
      for (int kf = 0; kf < 4; ++kf) {
        int row = kf * 16 + lc;
        unsigned byte = cur + row * 256 + ((((ks << 2) | lq) ^ (row & 7)) << 4);
        bf16x8 kh = *(const bf16x8*)(LDS + byte);
        bf16x8 kl = *(const bf16x8*)(LDS + byte + 16384);
        Sf[kf] = MFMA16(Qhi[ks], kh, Sf[kf]);
        Sf[kf] = MFMA16(Qlo[ks], kh, Sf[kf]);
        Sf[kf] = MFMA16(Qhi[ks], kl, Sf[kf]);
      }
    }

    // ---- online softmax (rows = lq*4+r, reduce over 16 lc lanes) ----
    float mloc[4] = {-1e30f, -1e30f, -1e30f, -1e30f};
#pragma unroll
    for (int kf = 0; kf < 4; ++kf) {
#pragma unroll
      for (int r = 0; r < 4; ++r) {
        int key = kc + kf * 16 + lc;
        float s = (key < n) ? Sf[kf][r] * scale : -1e30f;
        Sf[kf][r] = s;
        mloc[r] = fmaxf(mloc[r], s);
      }
    }
#pragma unroll
    for (int off = 1; off < 16; off <<= 1) {
#pragma unroll
      for (int r = 0; r < 4; ++r) mloc[r] = fmaxf(mloc[r], __shfl_xor(mloc[r], off, 64));
    }
    float corr[4], rs[4] = {0.f, 0.f, 0.f, 0.f};
#pragma unroll
    for (int r = 0; r < 4; ++r) {
      float mn = fmaxf(m_r[r], mloc[r]);
      corr[r] = expf(m_r[r] - mn);
      m_r[r] = mn;
    }
    // P = exp(S - m), split to bf16 hi/lo, write to wave-private swizzled LDS
#pragma unroll
    for (int kf = 0; kf < 4; ++kf) {
#pragma unroll
      for (int r = 0; r < 4; ++r) {
        float p = expf(Sf[kf][r] - m_r[r]);
        rs[r] += p;
        unsigned ph, plo;
        bsplit(p, ph, plo);
        int prow = (lq << 2) | r;
        int slot = (kf << 1) | (lc >> 3);
        unsigned pb = pbase + prow * 128 + ((slot ^ (prow & 7)) << 4) + ((lc & 7) << 1);
        *(u16*)(LDS + pb) = (u16)ph;
        *(u16*)(LDS + pb + 2048) = (u16)plo;
      }
    }
#pragma unroll
    for (int off = 1; off < 16; off <<= 1) {
#pragma unroll
      for (int r = 0; r < 4; ++r) rs[r] += __shfl_xor(rs[r], off, 64);
    }
#pragma unroll
    for (int r = 0; r < 4; ++r) l_r[r] = l_r[r] * corr[r] + rs[r];
#pragma unroll
    for (int df = 0; df < 8; ++df)
#pragma unroll
      for (int r = 0; r < 4; ++r) acc[df][r] *= corr[r];

    // ---- PV: A = P (from LDS, row=lc, keys lq*8), B = V (global vT) ----
#pragma unroll
    for (int ks2 = 0; ks2 < 2; ++ks2) {
      unsigned pr = pbase + lc * 128 + ((((ks2 << 2) | lq) ^ (lc & 7)) << 4);
      bf16x8 pa = *(const bf16x8*)(LDS + pr);
      bf16x8 pl = *(const bf16x8*)(LDS + pr + 2048);
#pragma unroll
      for (int df = 0; df < 8; ++df) {
        size_t vo = vbase + (size_t)(df * 16) * MAXN + kc + ks2 * 32;
        bf16x8 vh = *(const bf16x8*)(vT_hi + vo);
        bf16x8 vl = *(const bf16x8*)(vT_lo + vo);
        acc[df] = MFMA16(pa, vh, acc[df]);
        acc[df] = MFMA16(pl, vh, acc[df]);
        acc[df] = MFMA16(pa, vl, acc[df]);
      }
    }
    __syncthreads();
  }
#undef STAGEK

  // ---- epilogue: ctx rows = lq*4+r, col d = df*16+lc ----
#pragma unroll
  for (int r = 0; r < 4; ++r) {
    int rg = m0 + wid * 16 + (lq << 2) + r;
    if (rg < n) {
      int tok = idxg[rg];
      float inv = 1.0f / l_r[r];
      size_t o = (size_t)(b * Sn + tok) * HDn + lc;
#pragma unroll
      for (int df = 0; df < 8; ++df) {
        unsigned h, lo2;
        bsplit(acc[df][r] * inv, h, lo2);
        ctx_hi[o + df * 16] = (u16)h;
        ctx_lo[o + df * 16] = (u16)lo2;
      }
    }
  }
}

// ---------------- K5: out projection via MFMA bf16x3 + gate + scatter ----------------
__global__ __launch_bounds__(256) void k_out(
    const u16* __restrict__ ctx_hi, const u16* __restrict__ ctx_lo,
    const u16* __restrict__ WfT_hi, const u16* __restrict__ WfT_lo,
    const float* __restrict__ bff,
    const int* __restrict__ idx, const int* __restrict__ cnt,
    const int* __restrict__ tileg, const int* __restrict__ tilem,
    const int* __restrict__ ntile,
    const float* __restrict__ gateArr,
    float* __restrict__ out)
{
  int tid = blockIdx.x;
  if (tid >= ntile[0]) return;
  int g = tileg[tid], m0 = tilem[tid];
  int n = cnt[g];
  int b = g >> 3, e = g & 7;
  const int* idxg = idx + (g << 11);
  int t = threadIdx.x, wid = t >> 6, l = t & 63;
  int lc = l & 15, lq = l >> 4;
  int n0 = blockIdx.y * 256 + wid * 64;

  f32x4 acc[4][4];
#pragma unroll
  for (int i = 0; i < 4; ++i)
#pragma unroll
    for (int j = 0; j < 4; ++j) acc[i][j] = (f32x4){0.f, 0.f, 0.f, 0.f};

  size_t aoff[4];
#pragma unroll
  for (int fi = 0; fi < 4; ++fi) {
    int rg = m0 + fi * 16 + lc; rg = rg < n ? rg : n - 1;
    aoff[fi] = ((size_t)(b * Sn + idxg[rg])) * HDn + lq * 8;
  }
  size_t boff[4];
#pragma unroll
  for (int fj = 0; fj < 4; ++fj)
    boff[fj] = ((size_t)e * Dn + n0 + fj * 16 + lc) * HDn + lq * 8;

#pragma unroll
  for (int ks = 0; ks < 4; ++ks) {
    int ko = ks * 32;
    bf16x8 ah[4], al[4], bh[4], bl[4];
#pragma unroll
    for (int fi = 0; fi < 4; ++fi) {
      ah[fi] = *(const bf16x8*)(ctx_hi + aoff[fi] + ko);
      al[fi] = *(const bf16x8*)(ctx_lo + aoff[fi] + ko);
    }
#pragma unroll
    for (int fj = 0; fj < 4; ++fj) {
      bh[fj] = *(const bf16x8*)(WfT_hi + boff[fj] + ko);
      bl[fj] = *(const bf16x8*)(WfT_lo + boff[fj] + ko);
    }
#pragma unroll
    for (int fi = 0; fi < 4; ++fi)
#pragma unroll
      for (int fj = 0; fj < 4; ++fj) {
        acc[fi][fj] = MFMA16(ah[fi], bh[fj], acc[fi][fj]);
        acc[fi][fj] = MFMA16(al[fi], bh[fj], acc[fi][fj]);
        acc[fi][fj] = MFMA16(ah[fi], bl[fj], acc[fi][fj]);
      }
  }

  float bv[4];
#pragma unroll
  for (int fj = 0; fj < 4; ++fj) bv[fj] = bff[n0 + fj * 16 + lc];

#pragma unroll
  for (int fi = 0; fi < 4; ++fi) {
#pragma unroll
    for (int rr = 0; rr < 4; ++rr) {
      int rg = m0 + fi * 16 + lq * 4 + rr;
      if (rg < n) {
        int tok = idxg[rg];
        float gt = gateArr[b * Sn + tok];
        float* orow = out + ((size_t)(b * Sn + tok)) * Dn + n0 + lc;
#pragma unroll
        for (int fj = 0; fj < 4; ++fj)
          orow[fj * 16] = (acc[fi][fj][rr] + bv[fj]) * gt;
      }
    }
  }
}

extern "C" void kernel_launch(void* const* d_in, const int* in_sizes, int n_in,
                              void* d_out, int out_size, void* d_ws, size_t ws_size,
                              hipStream_t stream) {
  const float* x    = (const float*)d_in[0];
  const float* Wg   = (const float*)d_in[1];
  const float* Wqkv = (const float*)d_in[2];
  const float* Wff  = (const float*)d_in[3];
  const float* bff  = (const float*)d_in[4];
  const float* cosT = (const float*)d_in[5];
  const float* sinT = (const float*)d_in[6];
  float* out = (float*)d_out;

  size_t off = 0;
  auto carve = [&](size_t bytes) -> void* {
    void* p = (char*)d_ws + off;
    off += (bytes + 255) & ~(size_t)255;
    return p;
  };
  u16* xh_hi  = (u16*)carve((size_t)Bn * Sn * Dn * 2);
  u16* xh_lo  = (u16*)carve((size_t)Bn * Sn * Dn * 2);
  u16* WqT_hi = (u16*)carve((size_t)En * 384 * Dn * 2);
  u16* WqT_lo = (u16*)carve((size_t)En * 384 * Dn * 2);
  u16* WfT_hi = (u16*)carve((size_t)En * Dn * HDn * 2);
  u16* WfT_lo = (u16*)carve((size_t)En * Dn * HDn * 2);
  u16* qkv_hi = (u16*)carve((size_t)Bn * Sn * 384 * 2);
  u16* qkv_lo = (u16*)carve((size_t)Bn * Sn * 384 * 2);
  u16* vT_hi  = (u16*)carve((size_t)NG * HDn * MAXN * 2);
  u16* vT_lo  = (u16*)carve((size_t)NG * HDn * MAXN * 2);
  u16* ctx_hi = (u16*)carve((size_t)Bn * Sn * HDn * 2);
  u16* ctx_lo = (u16*)carve((size_t)Bn * Sn * HDn * 2);
  float* gateArr = (float*)carve((size_t)Bn * Sn * sizeof(float));
  int*   expertA = (int*)carve((size_t)Bn * Sn * sizeof(int));
  int*   idx     = (int*)carve((size_t)NG * Sn * sizeof(int));
  int*   cnt     = (int*)carve((size_t)NG * sizeof(int));
  int*   tileg   = (int*)carve((size_t)MAXT * sizeof(int));
  int*   tilem   = (int*)carve((size_t)MAXT * sizeof(int));
  int*   ntile   = (int*)carve(256);
  (void)ws_size; (void)in_sizes; (void)n_in; (void)out_size;

  hipFuncSetAttribute((const void*)k_attn, hipFuncAttributeMaxDynamicSharedMemorySize, 81920);

  k_rope_gate<<<dim3(Bn * Sn), dim3(256), 0, stream>>>(x, Wg, cosT, sinT, xh_hi, xh_lo, expertA, gateArr);
  k_prep_w<<<dim3(16, 6, 8), dim3(256), 0, stream>>>(Wqkv, WqT_hi, WqT_lo, Dn, 384);
  k_prep_w<<<dim3(2, 16, 8), dim3(256), 0, stream>>>(Wff, WfT_hi, WfT_lo, HDn, Dn);
  k_route<<<dim3(NG), dim3(256), 0, stream>>>(expertA, idx, cnt);
  k_tiles<<<dim3(1), dim3(64), 0, stream>>>(cnt, tileg, tilem, ntile);
  k_qkv<<<dim3(MAXT, 6), dim3(256), 65536, stream>>>(xh_hi, xh_lo, WqT_hi, WqT_lo, idx, cnt, tileg, tilem, ntile, qkv_hi, qkv_lo, vT_hi, vT_lo);
  k_attn<<<dim3(MAXT), dim3(256), 81920, stream>>>(qkv_hi, qkv_lo, vT_hi, vT_lo, idx, cnt, tileg, tilem, ntile, ctx_hi, ctx_lo);
  k_out<<<dim3(MAXT, 4), dim3(256), 0, stream>>>(ctx_hi, ctx_lo, WfT_hi, WfT_lo, bff, idx, cnt, tileg, tilem, ntile, gateArr, out);
}